// Round 7
// baseline (329.834 us; speedup 1.0000x reference)
//
#include <hip/hip_runtime.h>
#include <hip/hip_bf16.h>
#include <math.h>

// TFAlbertAttention  B=4,S=2048,D=1024,H=16,DH=64, fp32 in/out.
// cast->bf16 (+ mask pre-scale); QKV projections in ONE grid.z=3 launch of
//   the 128-tile MFMA GEMM; flash attention (4-wave blocks, K/V double-
//   buffered via global_load_lds with inverse-swizzled source, ONE barrier
//   per tile, swapped QK^T -> v_perm P pack + b64 P^T stores, XOR-swizzled
//   LDS, VMEM pre-scaled mask, row-sums via MFMA-ones); out GEMM; fused
//   residual+LayerNorm.
// NOTE: kernels use __launch_bounds__(256) with NO min-waves clause —
// (256,4) caps VGPR at 128 -> ~1.5GB scratch spill (round 1: 118->365us).
// NOTE: attn is LDS-ISSUE bound (round 6 analysis: 36 LDS ops/tile/wave ~=
// 77us/CU vs 37us MFMA): every change is judged by LDS-op count. R4's
// regression = qg-sequential PV (+8 vf reads); R5's = 2x waves re-staging.
// This round: staging->DMA (-4 LDS writes), mask->VMEM (-4 LDS reads).
// NOTE: no XCD swizzle in GEMMs — problem is L3-resident (round 5 negative).

#define B_ 4
#define S_ 2048
#define D_ 1024
#define H_ 16
#define DH_ 64
#define LN_EPS 1e-12f

typedef __attribute__((ext_vector_type(8))) short short8_;
typedef __attribute__((ext_vector_type(4))) short short4_;
typedef __attribute__((ext_vector_type(4))) float float4_;
typedef __attribute__((ext_vector_type(2))) int int2v;

__device__ inline short f2b(float x) {          // RNE
    unsigned u = __float_as_uint(x);
    unsigned r = (u + 0x7fffu + ((u >> 16) & 1u)) >> 16;
    return (short)r;
}

__device__ inline float4_ mfma16(short8_ a, short8_ b, float4_ c) {
    return __builtin_amdgcn_mfma_f32_16x16x32_bf16(a, b, c, 0, 0, 0);
}

#define GLOAD16(g, l)                                                      \
    __builtin_amdgcn_global_load_lds(                                      \
        (const __attribute__((address_space(1))) void*)(g),                \
        (__attribute__((address_space(3))) void*)(l), 16, 0, 0)

// ---------------- weight transpose + cast: W[k][n] fp32 -> Wt[n][k] bf16 ----
__global__ __launch_bounds__(256) void prep_weights(
    const float* __restrict__ W0, const float* __restrict__ W1,
    const float* __restrict__ W2, const float* __restrict__ W3,
    short* __restrict__ Wt)
{
    const float* W = (blockIdx.z == 0) ? W0 : (blockIdx.z == 1) ? W1
                   : (blockIdx.z == 2) ? W2 : W3;
    short* out = Wt + (size_t)blockIdx.z * (1024 * 1024);
    __shared__ float T[64][65];
    int tx = threadIdx.x & 63, ty = threadIdx.x >> 6;
    int k0 = blockIdx.x * 64, n0 = blockIdx.y * 64;
#pragma unroll
    for (int i = 0; i < 16; i++) {
        int kk = ty + i * 4;
        T[kk][tx] = W[(size_t)(k0 + kk) * 1024 + n0 + tx];
    }
    __syncthreads();
#pragma unroll
    for (int i = 0; i < 16; i++) {
        int nn = ty + i * 4;
        out[(size_t)(n0 + nn) * 1024 + k0 + tx] = f2b(T[tx][nn]);
    }
}

// ---------------- x fp32 -> bf16; tail blocks pre-scale mask ---------------
__global__ __launch_bounds__(256) void cast_x(const float* __restrict__ x,
                                              short* __restrict__ xb,
                                              const float* __restrict__ mask,
                                              float* __restrict__ mask2)
{
    const float LOG2E = 1.44269504f;
    int bid = blockIdx.x;
    if (bid < 8192) {
        int i = bid * 256 + threadIdx.x;
        float4_ v = ((const float4_*)x)[i];
        short4_ o;
#pragma unroll
        for (int j = 0; j < 4; j++) o[j] = f2b(v[j]);
        ((short4_*)xb)[i] = o;
    } else {
        int i = (bid - 8192) * 256 + threadIdx.x;   // 2048 float4 = B*S floats
        float4_ mv = ((const float4_*)mask)[i];
        ((float4_*)mask2)[i] = mv * LOG2E;
    }
}

// ---------------- fused QKV GEMM, grid (64, 8, 3) --------------------------
// z selects weight slice + destination: 0->Qb(+bq), 1->Kb(+bk), 2->Vtg(+bv,
// transposed per-head via T[64][132] aliased onto As/Bs LDS, dead after
// the K-loop). 128x128 tiles, BK=64 as two 32-sub-buffers, global_load_lds.
__global__ __launch_bounds__(256) void gemm_qkv(
    const short* __restrict__ A, const short* __restrict__ Wt,
    const float* __restrict__ bq, const float* __restrict__ bk,
    const float* __restrict__ bv,
    short* __restrict__ Qb, short* __restrict__ Kb, short* __restrict__ Vtg)
{
    __shared__ __align__(16) short SH[4 * 128 * 32];   // 32 KB
    short* As = SH;                                    // [2][128*32]
    short* Bs = SH + 2 * 128 * 32;                     // [2][128*32]
    const int K = D_;
    int tid = threadIdx.x;
    int wv = tid >> 6, lane = tid & 63;
    int g = lane >> 4, ln = lane & 15;
    int wm = wv & 1, wn = wv >> 1;
    int z = blockIdx.z;
    int mtile = blockIdx.x * 128, ntile = blockIdx.y * 128;
    const short* Bt = Wt + (size_t)z * (1024 * 1024);

    int srow = wv * 32 + (lane >> 2);
    int scol = (lane & 3) * 8;
    const short* agp = A + (size_t)(mtile + srow) * K + scol;
    const short* bgp = Bt + (size_t)(ntile + srow) * K + scol;

    float4_ acc[4][4];
#pragma unroll
    for (int i = 0; i < 4; i++)
#pragma unroll
        for (int j = 0; j < 4; j++) acc[i][j] = (float4_)(0.f);

    for (int k0 = 0; k0 < K; k0 += 64) {
        if (k0) __syncthreads();
#pragma unroll
        for (int hf = 0; hf < 2; hf++) {
            GLOAD16(agp + k0 + hf * 32, &As[hf * 4096 + (wv * 32) * 32]);
            GLOAD16(agp + k0 + hf * 32 + (size_t)16 * K, &As[hf * 4096 + (wv * 32 + 16) * 32]);
            GLOAD16(bgp + k0 + hf * 32, &Bs[hf * 4096 + (wv * 32) * 32]);
            GLOAD16(bgp + k0 + hf * 32 + (size_t)16 * K, &Bs[hf * 4096 + (wv * 32 + 16) * 32]);
        }
        __syncthreads();
#pragma unroll
        for (int hf = 0; hf < 2; hf++) {
            short8_ am[4], bn[4];
#pragma unroll
            for (int mt = 0; mt < 4; mt++)
                am[mt] = *(const short8_*)(&As[hf * 4096 + (wm * 64 + mt * 16 + ln) * 32 + g * 8]);
#pragma unroll
            for (int nt = 0; nt < 4; nt++)
                bn[nt] = *(const short8_*)(&Bs[hf * 4096 + (wn * 64 + nt * 16 + ln) * 32 + g * 8]);
#pragma unroll
            for (int mt = 0; mt < 4; mt++)
#pragma unroll
                for (int nt = 0; nt < 4; nt++)
                    acc[mt][nt] = mfma16(am[mt], bn[nt], acc[mt][nt]);
        }
    }

    if (z == 2) {
        // V: transpose per-head -> Vtg[bh][dh][s]. T[64][132] aliased on SH.
        short* T = SH;
        int b = mtile >> 11, s0 = mtile & 2047;
#pragma unroll
        for (int p = 0; p < 2; p++) {
            __syncthreads();
            if (wn == p) {
#pragma unroll
                for (int nt = 0; nt < 4; nt++) {
                    float bsv = bv[ntile + p * 64 + nt * 16 + ln];
#pragma unroll
                    for (int mt = 0; mt < 4; mt++) {
                        short4_ o;
#pragma unroll
                        for (int r = 0; r < 4; r++) o[r] = f2b(acc[mt][nt][r] + bsv);
                        *(short4_*)(&T[(nt * 16 + ln) * 132 + wm * 64 + mt * 16 + g * 4]) = o;
                    }
                }
            }
            __syncthreads();
            int h = (ntile >> 6) + p;
            int row = tid >> 2, colb = (tid & 3) * 32;
            size_t obase = ((size_t)(b * H_ + h)) * (DH_ * S_) + (size_t)row * S_ + s0 + colb;
#pragma unroll
            for (int c = 0; c < 4; c++)
                *(short8_*)(Vtg + obase + c * 8) = *(const short8_*)(&T[row * 132 + colb + c * 8]);
        }
    } else {
        short* Cout = z ? Kb : Qb;
        const float* bias = z ? bk : bq;
#pragma unroll
        for (int nt = 0; nt < 4; nt++) {
            int n = ntile + wn * 64 + nt * 16 + ln;
            float bsv = bias[n];
#pragma unroll
            for (int mt = 0; mt < 4; mt++) {
#pragma unroll
                for (int r = 0; r < 4; r++) {
                    int m = mtile + wm * 64 + mt * 16 + g * 4 + r;
                    Cout[(size_t)m * D_ + n] = f2b(acc[mt][nt][r] + bsv);
                }
            }
        }
    }
}

// ---------------- out GEMM: Ctx[8192,1024] x Wo^T + bo -> bf16 -------------
__global__ __launch_bounds__(256) void gemm_out(
    const short* __restrict__ A, const short* __restrict__ Bt,
    const float* __restrict__ bias, short* __restrict__ Cout)
{
    __shared__ __align__(16) short As[2][128 * 32];
    __shared__ __align__(16) short Bs[2][128 * 32];
    const int K = D_;
    int tid = threadIdx.x;
    int wv = tid >> 6, lane = tid & 63;
    int g = lane >> 4, ln = lane & 15;
    int wm = wv & 1, wn = wv >> 1;
    int mtile = blockIdx.x * 128, ntile = blockIdx.y * 128;

    int srow = wv * 32 + (lane >> 2);
    int scol = (lane & 3) * 8;
    const short* agp = A + (size_t)(mtile + srow) * K + scol;
    const short* bgp = Bt + (size_t)(ntile + srow) * K + scol;

    float4_ acc[4][4];
#pragma unroll
    for (int i = 0; i < 4; i++)
#pragma unroll
        for (int j = 0; j < 4; j++) acc[i][j] = (float4_)(0.f);

    for (int k0 = 0; k0 < K; k0 += 64) {
        if (k0) __syncthreads();
#pragma unroll
        for (int hf = 0; hf < 2; hf++) {
            GLOAD16(agp + k0 + hf * 32, &As[hf][(wv * 32) * 32]);
            GLOAD16(agp + k0 + hf * 32 + (size_t)16 * K, &As[hf][(wv * 32 + 16) * 32]);
            GLOAD16(bgp + k0 + hf * 32, &Bs[hf][(wv * 32) * 32]);
            GLOAD16(bgp + k0 + hf * 32 + (size_t)16 * K, &Bs[hf][(wv * 32 + 16) * 32]);
        }
        __syncthreads();
#pragma unroll
        for (int hf = 0; hf < 2; hf++) {
            short8_ am[4], bn[4];
#pragma unroll
            for (int mt = 0; mt < 4; mt++)
                am[mt] = *(const short8_*)(&As[hf][(wm * 64 + mt * 16 + ln) * 32 + g * 8]);
#pragma unroll
            for (int nt = 0; nt < 4; nt++)
                bn[nt] = *(const short8_*)(&Bs[hf][(wn * 64 + nt * 16 + ln) * 32 + g * 8]);
#pragma unroll
            for (int mt = 0; mt < 4; mt++)
#pragma unroll
                for (int nt = 0; nt < 4; nt++)
                    acc[mt][nt] = mfma16(am[mt], bn[nt], acc[mt][nt]);
        }
    }

#pragma unroll
    for (int nt = 0; nt < 4; nt++) {
        int n = ntile + wn * 64 + nt * 16 + ln;
        float bsv = bias[n];
#pragma unroll
        for (int mt = 0; mt < 4; mt++) {
#pragma unroll
            for (int r = 0; r < 4; r++) {
                int m = mtile + wm * 64 + mt * 16 + g * 4 + r;
                Cout[(size_t)m * D_ + n] = f2b(acc[mt][nt][r] + bsv);
            }
        }
    }
}

// ---------------- flash attention (m=0 softmax, exp2-fma) ------------------
// grid (S/128, B*H). block 256 = 4 waves; wave owns 32 q rows (2 groups of 16).
// K/V double-buffered in LDS, staged by global_load_lds (linear LDS dest,
// inverse-swizzled per-lane global source -> reads see XOR-swizzled layout).
// ONE barrier per KV tile: each wave's barrier drains its own DMA (vmcnt 0)
// so buf[cur] is complete and prev readers of buf[cur^1] are retired; the
// next tile's DMA then flies under this tile's full compute.
// SWAPPED QK^T: lane holds P[q=ln][4 consecutive keys] -> v_perm pack + b64
// P^T stores; PV (R6 interleave: vf shared across qg) reads b128 A-frags.
// Mask pre-scaled (mask*log2e, VMEM) — no LDS involvement.
// Row-sums via MFMA-ones (denominator lands in the epilogue's registers).
// LDS ops/tile/wave: kf 8r + PT 8w + vf 8r + pa 4r = 28 (was 36).
__global__ __launch_bounds__(256) void attn(
    const short* __restrict__ Qb, const short* __restrict__ Kb,
    const short* __restrict__ Vtg, const float* __restrict__ mask2,
    short* __restrict__ ctx)
{
    __shared__ __align__(16) short Ks[2][64 * 64];    // [key][d], swizzled
    __shared__ __align__(16) short Vs[2][64 * 64];    // [d][key], swizzled
    __shared__ __align__(16) short PT[4 * 32 * 64];   // per-wave [q][key], swizzled
    int tid = threadIdx.x, wv = tid >> 6, lane = tid & 63;
    int g = lane >> 4, ln = lane & 15;
    int qt = blockIdx.x, bh = blockIdx.y;
    int b = bh >> 4, h = bh & 15;
    const size_t base = (size_t)b * S_ * D_ + h * DH_;
    const size_t vbase = (size_t)bh * (DH_ * S_);
    const float C1 = 0.18033688f;       // 0.125 * log2(e)
    const int px = (ln & 7) << 3;       // read-side XOR (row&7 == ln&7)

    // staging: lane l covers row (l>>3) of an 8-row stripe; source col is
    // pre-XORed so the linear LDS dest ends up swizzled exactly like px.
    int rl = lane >> 3;
    int cl = ((lane & 7) ^ rl) << 3;                  // shorts
    const short* kg = Kb + base + (size_t)(wv * 16 + rl) * D_ + cl;
    const short* vg = Vtg + vbase + (size_t)(wv * 16 + rl) * S_ + cl;

#define STAGE_KV(bufsel, kt_)                                               \
    do {                                                                    \
        size_t ko = (size_t)(kt_) * 64 * D_;                                \
        size_t vo = (size_t)(kt_) * 64;                                     \
        GLOAD16(kg + ko,                  &Ks[bufsel][(wv * 16) * 64]);     \
        GLOAD16(kg + ko + (size_t)8 * D_, &Ks[bufsel][(wv * 16 + 8) * 64]); \
        GLOAD16(vg + vo,                  &Vs[bufsel][(wv * 16) * 64]);     \
        GLOAD16(vg + vo + (size_t)8 * S_, &Vs[bufsel][(wv * 16 + 8) * 64]); \
    } while (0)

    short8_ aq[2][2];
#pragma unroll
    for (int qg = 0; qg < 2; qg++) {
        int qrow = qt * 128 + wv * 32 + qg * 16 + ln;
        aq[qg][0] = *(const short8_*)(Qb + base + (size_t)qrow * D_ + g * 8);
        aq[qg][1] = *(const short8_*)(Qb + base + (size_t)qrow * D_ + 32 + g * 8);
    }

    short8_ vones;                      // bf16 1.0 x8 (B-operand for row-sums)
#pragma unroll
    for (int j = 0; j < 8; j++) vones[j] = (short)0x3F80;

    float4_ O[2][4];
    float4_ lsacc[2];
#pragma unroll
    for (int qg = 0; qg < 2; qg++) {
        lsacc[qg] = (float4_)(0.f);
#pragma unroll
        for (int i = 0; i < 4; i++) O[qg][i] = (float4_)(0.f);
    }

    const float* mrow = mask2 + (size_t)b * S_ + g * 4;

    STAGE_KV(0, 0);                     // prologue DMA for tile 0
    int cur = 0;

    for (int kt = 0; kt < S_ / 64; kt++) {
        __syncthreads();                // buf[cur] DMA drained + prev readers done
        if (kt < S_ / 64 - 1) STAGE_KV(cur ^ 1, kt + 1);

        float4_ mk4[4];                 // pre-scaled mask, keys nt*16+g*4..+3
#pragma unroll
        for (int nt = 0; nt < 4; nt++)
            mk4[nt] = *(const float4_*)(mrow + kt * 64 + nt * 16);

        const short* KsC = &Ks[cur][0];
        const short* VsC = &Vs[cur][0];

        short8_ kf[4][2];
#pragma unroll
        for (int nt = 0; nt < 4; nt++) {
            kf[nt][0] = *(const short8_*)(&KsC[(nt * 16 + ln) * 64 + ((g * 8) ^ px)]);
            kf[nt][1] = *(const short8_*)(&KsC[(nt * 16 + ln) * 64 + ((32 + g * 8) ^ px)]);
        }

#pragma unroll
        for (int qg = 0; qg < 2; qg++) {
            float4_ Sf[4];
            __builtin_amdgcn_s_setprio(1);
#pragma unroll
            for (int nt = 0; nt < 4; nt++) {
                float4_ s = (float4_)(0.f);
                s = mfma16(kf[nt][0], aq[qg][0], s);   // swapped: A=K, B=Q
                s = mfma16(kf[nt][1], aq[qg][1], s);
                Sf[nt] = s;
            }
            __builtin_amdgcn_s_setprio(0);
            int prow = wv * 2048 + (qg * 16 + ln) * 64;
#pragma unroll
            for (int nt = 0; nt < 4; nt++) {
                float p0 = __builtin_amdgcn_exp2f(fmaf(Sf[nt][0], C1, mk4[nt][0]));
                float p1 = __builtin_amdgcn_exp2f(fmaf(Sf[nt][1], C1, mk4[nt][1]));
                float p2 = __builtin_amdgcn_exp2f(fmaf(Sf[nt][2], C1, mk4[nt][2]));
                float p3 = __builtin_amdgcn_exp2f(fmaf(Sf[nt][3], C1, mk4[nt][3]));
                // pack 4 f32 -> 4 bf16 (trunc) with two v_perm_b32
                int2v w;
                w[0] = (int)__builtin_amdgcn_perm(__float_as_uint(p1),
                                                  __float_as_uint(p0), 0x07060302u);
                w[1] = (int)__builtin_amdgcn_perm(__float_as_uint(p3),
                                                  __float_as_uint(p2), 0x07060302u);
                *(int2v*)(&PT[prow + ((nt * 16 + g * 4) ^ px)]) = w;
            }
        }

#pragma unroll
        for (int ks = 0; ks < 2; ks++) {
            short8_ vf[4];
#pragma unroll
            for (int dt = 0; dt < 4; dt++)
                vf[dt] = *(const short8_*)(&VsC[(dt * 16 + ln) * 64 + ((ks * 32 + g * 8) ^ px)]);
#pragma unroll
            for (int qg = 0; qg < 2; qg++) {
                short8_ pa = *(const short8_*)(
                    &PT[wv * 2048 + (qg * 16 + ln) * 64 + ((ks * 32 + g * 8) ^ px)]);
                __builtin_amdgcn_s_setprio(1);
#pragma unroll
                for (int dt = 0; dt < 4; dt++)
                    O[qg][dt] = mfma16(pa, vf[dt], O[qg][dt]);
                lsacc[qg] = mfma16(pa, vones, lsacc[qg]);   // row-sum column
                __builtin_amdgcn_s_setprio(0);
            }
        }
        cur ^= 1;
    }
#undef STAGE_KV

    // lsacc[qg][r] = full softmax denominator for q = qg*16 + g*4 + r
    // (identical across ln cols) — exactly the rows this thread stores.
#pragma unroll
    for (int qg = 0; qg < 2; qg++) {
        float inv[4];
#pragma unroll
        for (int r = 0; r < 4; r++) inv[r] = 1.f / lsacc[qg][r];
#pragma unroll
        for (int dt = 0; dt < 4; dt++)
#pragma unroll
            for (int r = 0; r < 4; r++) {
                int q = qt * 128 + wv * 32 + qg * 16 + g * 4 + r;
                float v = O[qg][dt][r] * inv[r];
                ctx[base + (size_t)q * D_ + dt * 16 + ln] = f2b(v);
            }
    }
}

// ---------------- residual + LayerNorm (h in bf16) -------------------------
__global__ __launch_bounds__(256) void ln_kernel(
    const short* __restrict__ hb, const float* __restrict__ x,
    const float* __restrict__ gamma, const float* __restrict__ beta,
    float* __restrict__ out)
{
    int row = blockIdx.x, tid = threadIdx.x;
    const short* hr = hb + (size_t)row * D_;
    const float* xr = x + (size_t)row * D_;
    short4_ h4 = ((const short4_*)hr)[tid];
    float4_ x4 = ((const float4_*)xr)[tid];
    float y[4], s1 = 0.f, s2 = 0.f;
#pragma unroll
    for (int i = 0; i < 4; i++) {
        float hv = __uint_as_float(((unsigned)(unsigned short)h4[i]) << 16);
        float v = hv + x4[i];
        y[i] = v;
        s1 += v;
        s2 += v * v;
    }
#pragma unroll
    for (int sh = 1; sh < 64; sh <<= 1) {
        s1 += __shfl_xor(s1, sh);
        s2 += __shfl_xor(s2, sh);
    }
    __shared__ float ws1[4], ws2[4];
    if ((tid & 63) == 0) { ws1[tid >> 6] = s1; ws2[tid >> 6] = s2; }
    __syncthreads();
    s1 = ws1[0] + ws1[1] + ws1[2] + ws1[3];
    s2 = ws2[0] + ws2[1] + ws2[2] + ws2[3];
    float mu = s1 * (1.f / D_);
    float var = s2 * (1.f / D_) - mu * mu;
    float rs = rsqrtf(var + LN_EPS);
    float4_ g4 = ((const float4_*)gamma)[tid];
    float4_ b4 = ((const float4_*)beta)[tid];
    float4_ o4;
#pragma unroll
    for (int i = 0; i < 4; i++) o4[i] = (y[i] - mu) * rs * g4[i] + b4[i];
    ((float4_*)(out + (size_t)row * D_))[tid] = o4;
}

extern "C" void kernel_launch(void* const* d_in, const int* in_sizes, int n_in,
                              void* d_out, int out_size, void* d_ws, size_t ws_size,
                              hipStream_t stream)
{
    const float* x     = (const float*)d_in[0];
    const float* mask  = (const float*)d_in[1];
    const float* Wq    = (const float*)d_in[2];
    const float* bq    = (const float*)d_in[3];
    const float* Wk    = (const float*)d_in[4];
    const float* bk    = (const float*)d_in[5];
    const float* Wv    = (const float*)d_in[6];
    const float* bv    = (const float*)d_in[7];
    const float* Wo    = (const float*)d_in[8];
    const float* bo    = (const float*)d_in[9];
    const float* gamma = (const float*)d_in[10];
    const float* beta  = (const float*)d_in[11];
    float* out = (float*)d_out;

    char* ws = (char*)d_ws;
    const size_t MB = 1024 * 1024;
    short* Wt   = (short*)(ws);              // 8 MB (Wq,Wk,Wv,Wo transposed)
    short* Xb   = (short*)(ws + 8 * MB);     // 16 MB (reused for Ctx)
    short* Qb   = (short*)(ws + 24 * MB);    // 16 MB (reused for Hh)
    short* Kb   = (short*)(ws + 40 * MB);    // 16 MB
    short* Vtg  = (short*)(ws + 56 * MB);    // 16 MB, [bh][dh][s]
    float* msk2 = (float*)(ws + 72 * MB);    // 32 KB, mask * log2(e)
    short* Ctx = Xb;
    short* Hh  = Qb;                        // Qb dead after attn

    prep_weights<<<dim3(16, 16, 4), 256, 0, stream>>>(Wq, Wk, Wv, Wo, Wt);
    cast_x<<<8192 + 8, 256, 0, stream>>>(x, Xb, mask, msk2);

    gemm_qkv<<<dim3(64, 8, 3), 256, 0, stream>>>(Xb, Wt, bq, bk, bv, Qb, Kb, Vtg);

    attn<<<dim3(S_ / 128, B_ * H_), 256, 0, stream>>>(Qb, Kb, Vtg, msk2, Ctx);

    gemm_out<<<dim3(64, 8), 256, 0, stream>>>(Ctx, Wt + 3 * 1048576, bo, Hh);

    ln_kernel<<<B_ * S_, 256, 0, stream>>>(Hh, x, gamma, beta, out);
}

// Round 8
// 318.296 us; speedup vs baseline: 1.0362x; 1.0362x over previous
//
#include <hip/hip_runtime.h>
#include <hip/hip_bf16.h>
#include <math.h>

// TFAlbertAttention  B=4,S=2048,D=1024,H=16,DH=64, fp32 in/out.
// cast->bf16; QKV projections in ONE grid.z=3 launch of the 128-tile MFMA
//   GEMM; flash attention (R6 structure, measured 119.4us — FROZEN);
//   out GEMM with 64x128 tiles (1024 blocks = 4/CU demand vs 2/CU for 128^2;
//   the out-GEMM was grid-capped at 2 resident blocks/CU = ~410 TF);
//   fused residual+LayerNorm.
// NOTE: kernels use __launch_bounds__(256) with NO min-waves clause —
// (256,4) caps VGPR at 128 -> ~1.5GB scratch spill (round 1: 118->365us).
// NOTE: attn structure is FROZEN at the R6 variant. Measured across 7
// restructurings (118.7/365/137.6/121.3/136.7/138.2/119.4/129.9):
//   - ds_write staging + 2 barriers/tile BEATS global_load_lds dbuf +
//     1 barrier (R4/R7: LDS 49KB -> 3 blocks/CU vs 4 needed -> tail pass).
//   - interleaved PV (vf shared across qg) beats qg-sequential (R4).
//   - QBLK=128/4-wave beats QBLK=64 (R5: 2x waves re-stage all K/V).
//   - mask via LDS (Ms) beats per-nt VMEM loads measured in-loop (R2).
//   - row-sums via MFMA-ones beats shuffle tree (R3, also absmax 2x better).
// NOTE: no XCD swizzle in GEMMs — problem is L3-resident (round 5 negative).

#define B_ 4
#define S_ 2048
#define D_ 1024
#define H_ 16
#define DH_ 64
#define LN_EPS 1e-12f

typedef __attribute__((ext_vector_type(8))) short short8_;
typedef __attribute__((ext_vector_type(4))) short short4_;
typedef __attribute__((ext_vector_type(4))) float float4_;
typedef __attribute__((ext_vector_type(2))) int int2v;

__device__ inline short f2b(float x) {          // RNE
    unsigned u = __float_as_uint(x);
    unsigned r = (u + 0x7fffu + ((u >> 16) & 1u)) >> 16;
    return (short)r;
}

__device__ inline float4_ mfma16(short8_ a, short8_ b, float4_ c) {
    return __builtin_amdgcn_mfma_f32_16x16x32_bf16(a, b, c, 0, 0, 0);
}

#define GLOAD16(g, l)                                                      \
    __builtin_amdgcn_global_load_lds(                                      \
        (const __attribute__((address_space(1))) void*)(g),                \
        (__attribute__((address_space(3))) void*)(l), 16, 0, 0)

// ---------------- weight transpose + cast: W[k][n] fp32 -> Wt[n][k] bf16 ----
__global__ __launch_bounds__(256) void prep_weights(
    const float* __restrict__ W0, const float* __restrict__ W1,
    const float* __restrict__ W2, const float* __restrict__ W3,
    short* __restrict__ Wt)
{
    const float* W = (blockIdx.z == 0) ? W0 : (blockIdx.z == 1) ? W1
                   : (blockIdx.z == 2) ? W2 : W3;
    short* out = Wt + (size_t)blockIdx.z * (1024 * 1024);
    __shared__ float T[64][65];
    int tx = threadIdx.x & 63, ty = threadIdx.x >> 6;
    int k0 = blockIdx.x * 64, n0 = blockIdx.y * 64;
#pragma unroll
    for (int i = 0; i < 16; i++) {
        int kk = ty + i * 4;
        T[kk][tx] = W[(size_t)(k0 + kk) * 1024 + n0 + tx];
    }
    __syncthreads();
#pragma unroll
    for (int i = 0; i < 16; i++) {
        int nn = ty + i * 4;
        out[(size_t)(n0 + nn) * 1024 + k0 + tx] = f2b(T[tx][nn]);
    }
}

// ---------------- x fp32 -> bf16 ----------------
__global__ __launch_bounds__(256) void cast_x(const float* __restrict__ x,
                                              short* __restrict__ xb)
{
    int i = blockIdx.x * 256 + threadIdx.x;
    float4_ v = ((const float4_*)x)[i];
    short4_ o;
#pragma unroll
    for (int j = 0; j < 4; j++) o[j] = f2b(v[j]);
    ((short4_*)xb)[i] = o;
}

// ---------------- fused QKV GEMM, grid (64, 8, 3) --------------------------
// z selects weight slice + destination: 0->Qb(+bq), 1->Kb(+bk), 2->Vtg(+bv,
// transposed per-head via T[64][132] aliased onto As/Bs LDS, dead after
// the K-loop). 128x128 tiles, BK=64 as two 32-sub-buffers, global_load_lds.
__global__ __launch_bounds__(256) void gemm_qkv(
    const short* __restrict__ A, const short* __restrict__ Wt,
    const float* __restrict__ bq, const float* __restrict__ bk,
    const float* __restrict__ bv,
    short* __restrict__ Qb, short* __restrict__ Kb, short* __restrict__ Vtg)
{
    __shared__ __align__(16) short SH[4 * 128 * 32];   // 32 KB
    short* As = SH;                                    // [2][128*32]
    short* Bs = SH + 2 * 128 * 32;                     // [2][128*32]
    const int K = D_;
    int tid = threadIdx.x;
    int wv = tid >> 6, lane = tid & 63;
    int g = lane >> 4, ln = lane & 15;
    int wm = wv & 1, wn = wv >> 1;
    int z = blockIdx.z;
    int mtile = blockIdx.x * 128, ntile = blockIdx.y * 128;
    const short* Bt = Wt + (size_t)z * (1024 * 1024);

    int srow = wv * 32 + (lane >> 2);
    int scol = (lane & 3) * 8;
    const short* agp = A + (size_t)(mtile + srow) * K + scol;
    const short* bgp = Bt + (size_t)(ntile + srow) * K + scol;

    float4_ acc[4][4];
#pragma unroll
    for (int i = 0; i < 4; i++)
#pragma unroll
        for (int j = 0; j < 4; j++) acc[i][j] = (float4_)(0.f);

    for (int k0 = 0; k0 < K; k0 += 64) {
        if (k0) __syncthreads();
#pragma unroll
        for (int hf = 0; hf < 2; hf++) {
            GLOAD16(agp + k0 + hf * 32, &As[hf * 4096 + (wv * 32) * 32]);
            GLOAD16(agp + k0 + hf * 32 + (size_t)16 * K, &As[hf * 4096 + (wv * 32 + 16) * 32]);
            GLOAD16(bgp + k0 + hf * 32, &Bs[hf * 4096 + (wv * 32) * 32]);
            GLOAD16(bgp + k0 + hf * 32 + (size_t)16 * K, &Bs[hf * 4096 + (wv * 32 + 16) * 32]);
        }
        __syncthreads();
#pragma unroll
        for (int hf = 0; hf < 2; hf++) {
            short8_ am[4], bn[4];
#pragma unroll
            for (int mt = 0; mt < 4; mt++)
                am[mt] = *(const short8_*)(&As[hf * 4096 + (wm * 64 + mt * 16 + ln) * 32 + g * 8]);
#pragma unroll
            for (int nt = 0; nt < 4; nt++)
                bn[nt] = *(const short8_*)(&Bs[hf * 4096 + (wn * 64 + nt * 16 + ln) * 32 + g * 8]);
#pragma unroll
            for (int mt = 0; mt < 4; mt++)
#pragma unroll
                for (int nt = 0; nt < 4; nt++)
                    acc[mt][nt] = mfma16(am[mt], bn[nt], acc[mt][nt]);
        }
    }

    if (z == 2) {
        // V: transpose per-head -> Vtg[bh][dh][s]. T[64][132] aliased on SH.
        short* T = SH;
        int b = mtile >> 11, s0 = mtile & 2047;
#pragma unroll
        for (int p = 0; p < 2; p++) {
            __syncthreads();
            if (wn == p) {
#pragma unroll
                for (int nt = 0; nt < 4; nt++) {
                    float bsv = bv[ntile + p * 64 + nt * 16 + ln];
#pragma unroll
                    for (int mt = 0; mt < 4; mt++) {
                        short4_ o;
#pragma unroll
                        for (int r = 0; r < 4; r++) o[r] = f2b(acc[mt][nt][r] + bsv);
                        *(short4_*)(&T[(nt * 16 + ln) * 132 + wm * 64 + mt * 16 + g * 4]) = o;
                    }
                }
            }
            __syncthreads();
            int h = (ntile >> 6) + p;
            int row = tid >> 2, colb = (tid & 3) * 32;
            size_t obase = ((size_t)(b * H_ + h)) * (DH_ * S_) + (size_t)row * S_ + s0 + colb;
#pragma unroll
            for (int c = 0; c < 4; c++)
                *(short8_*)(Vtg + obase + c * 8) = *(const short8_*)(&T[row * 132 + colb + c * 8]);
        }
    } else {
        short* Cout = z ? Kb : Qb;
        const float* bias = z ? bk : bq;
#pragma unroll
        for (int nt = 0; nt < 4; nt++) {
            int n = ntile + wn * 64 + nt * 16 + ln;
            float bsv = bias[n];
#pragma unroll
            for (int mt = 0; mt < 4; mt++) {
#pragma unroll
                for (int r = 0; r < 4; r++) {
                    int m = mtile + wm * 64 + mt * 16 + g * 4 + r;
                    Cout[(size_t)m * D_ + n] = f2b(acc[mt][nt][r] + bsv);
                }
            }
        }
    }
}

// ---------------- out GEMM: Ctx[8192,1024] x Wo^T + bo -> bf16 -------------
// 64x128 tiles, grid (128, 8) = 1024 blocks -> 4 blocks/CU demand (the 128^2
// version was grid-capped at 2 resident blocks/CU = ~410 TF). LDS 24KB ->
// up to 6 resident/CU. Wave owns 32m x 64n (acc 2x4 fragments = 32 VGPR).
__global__ __launch_bounds__(256) void gemm_out(
    const short* __restrict__ A, const short* __restrict__ Bt,
    const float* __restrict__ bias, short* __restrict__ Cout)
{
    __shared__ __align__(16) short As[2][64 * 32];    // 8 KB
    __shared__ __align__(16) short Bs[2][128 * 32];   // 16 KB
    const int K = D_;
    int tid = threadIdx.x;
    int wv = tid >> 6, lane = tid & 63;
    int g = lane >> 4, ln = lane & 15;
    int wm = wv & 1, wn = wv >> 1;
    int mtile = blockIdx.x * 64, ntile = blockIdx.y * 128;

    int arow = wv * 16 + (lane >> 2);    // wave stages 16 A-rows
    int brow = wv * 32 + (lane >> 2);    // wave stages 32 B-rows (2 gloads)
    int scol = (lane & 3) * 8;
    const short* agp = A + (size_t)(mtile + arow) * K + scol;
    const short* bgp = Bt + (size_t)(ntile + brow) * K + scol;

    float4_ acc[2][4];
#pragma unroll
    for (int i = 0; i < 2; i++)
#pragma unroll
        for (int j = 0; j < 4; j++) acc[i][j] = (float4_)(0.f);

    for (int k0 = 0; k0 < K; k0 += 64) {
        if (k0) __syncthreads();
#pragma unroll
        for (int hf = 0; hf < 2; hf++) {
            GLOAD16(agp + k0 + hf * 32, &As[hf][(wv * 16) * 32]);
            GLOAD16(bgp + k0 + hf * 32, &Bs[hf][(wv * 32) * 32]);
            GLOAD16(bgp + k0 + hf * 32 + (size_t)16 * K, &Bs[hf][(wv * 32 + 16) * 32]);
        }
        __syncthreads();
#pragma unroll
        for (int hf = 0; hf < 2; hf++) {
            short8_ am[2], bn[4];
#pragma unroll
            for (int mt = 0; mt < 2; mt++)
                am[mt] = *(const short8_*)(&As[hf][(wm * 32 + mt * 16 + ln) * 32 + g * 8]);
#pragma unroll
            for (int nt = 0; nt < 4; nt++)
                bn[nt] = *(const short8_*)(&Bs[hf][(wn * 64 + nt * 16 + ln) * 32 + g * 8]);
#pragma unroll
            for (int mt = 0; mt < 2; mt++)
#pragma unroll
                for (int nt = 0; nt < 4; nt++)
                    acc[mt][nt] = mfma16(am[mt], bn[nt], acc[mt][nt]);
        }
    }

#pragma unroll
    for (int nt = 0; nt < 4; nt++) {
        int n = ntile + wn * 64 + nt * 16 + ln;
        float bsv = bias[n];
#pragma unroll
        for (int mt = 0; mt < 2; mt++) {
#pragma unroll
            for (int r = 0; r < 4; r++) {
                int m = mtile + wm * 32 + mt * 16 + g * 4 + r;
                Cout[(size_t)m * D_ + n] = f2b(acc[mt][nt][r] + bsv);
            }
        }
    }
}

// ---------------- flash attention (R6 structure — FROZEN) ------------------
// grid (S/128, B*H). block 256 = 4 waves; wave owns 32 q rows (2 groups of 16).
// SWAPPED QK^T: S^T = mfma(Kfrag, Qfrag) -> lane holds P[q=ln][4 consecutive
// keys per nt] -> v_perm bf16 pack + b64 P^T stores, b128 A-frag reads for PV.
// Row-sums via an extra MFMA against ones (denominator lands in the exact
// register the epilogue needs; zero cross-lane traffic).
// Mask pre-scaled by log2(e) and staged in LDS once per block.
// All LDS tiles XOR-swizzled. K/V loads for tile kt+1 issued before compute
// of tile kt (latency hidden under MFMA).
__global__ __launch_bounds__(256) void attn(
    const short* __restrict__ Qb, const short* __restrict__ Kb,
    const short* __restrict__ Vtg, const float* __restrict__ mask,
    short* __restrict__ ctx)
{
    __shared__ __align__(16) short Ks[64 * 64];       // [key][d], swizzled
    __shared__ __align__(16) short Vs[64 * 64];       // [d][key], swizzled
    __shared__ __align__(16) short PT[4 * 32 * 64];   // per-wave [q][key], swizzled
    __shared__ __align__(16) float Ms[S_];            // mask[b] * log2(e)
    int tid = threadIdx.x, wv = tid >> 6, lane = tid & 63;
    int g = lane >> 4, ln = lane & 15;
    int qt = blockIdx.x, bh = blockIdx.y;
    int b = bh >> 4, h = bh & 15;
    const size_t base = (size_t)b * S_ * D_ + h * DH_;
    const size_t vbase = (size_t)bh * (DH_ * S_);
    const float C1 = 0.18033688f;       // 0.125 * log2(e)
    const float LOG2E = 1.44269504f;
    const int px = (ln & 7) << 3;       // read-side XOR (row&7 == ln&7)

    // stage pre-scaled mask row into LDS (once per block)
#pragma unroll
    for (int i = 0; i < 2; i++) {
        float4_ mv = *(const float4_*)(mask + (size_t)b * S_ + i * 1024 + tid * 4);
        *(float4_*)(&Ms[i * 1024 + tid * 4]) = mv * LOG2E;
    }

    short8_ aq[2][2];
#pragma unroll
    for (int qg = 0; qg < 2; qg++) {
        int qrow = qt * 128 + wv * 32 + qg * 16 + ln;
        aq[qg][0] = *(const short8_*)(Qb + base + (size_t)qrow * D_ + g * 8);
        aq[qg][1] = *(const short8_*)(Qb + base + (size_t)qrow * D_ + 32 + g * 8);
    }

    short8_ vones;                      // bf16 1.0 x8 (B-operand for row-sums)
#pragma unroll
    for (int j = 0; j < 8; j++) vones[j] = (short)0x3F80;

    float4_ O[2][4];
    float4_ lsacc[2];
#pragma unroll
    for (int qg = 0; qg < 2; qg++) {
        lsacc[qg] = (float4_)(0.f);
#pragma unroll
        for (int i = 0; i < 4; i++) O[qg][i] = (float4_)(0.f);
    }

    // staging addresses (loop-invariant)
    int srow = tid >> 2, scol = (tid & 3) * 16;
    int sw0 = srow * 64 + (scol ^ ((srow & 7) << 3));
    int sw1 = srow * 64 + ((scol + 8) ^ ((srow & 7) << 3));

    const short* kp = Kb + base + (size_t)srow * D_ + scol;
    const short* vp = Vtg + vbase + (size_t)srow * S_ + scol;

    // prologue: load tile 0 into regs
    short8_ k0 = *(const short8_*)(kp);
    short8_ k1 = *(const short8_*)(kp + 8);
    short8_ v0 = *(const short8_*)(vp);
    short8_ v1 = *(const short8_*)(vp + 8);
    kp += (size_t)64 * D_;
    vp += 64;

    for (int kt = 0; kt < S_ / 64; kt++) {
        __syncthreads();                       // all waves done reading prev tile
        *(short8_*)(&Ks[sw0]) = k0;
        *(short8_*)(&Ks[sw1]) = k1;
        *(short8_*)(&Vs[sw0]) = v0;
        *(short8_*)(&Vs[sw1]) = v1;
        __syncthreads();
        if (kt < S_ / 64 - 1) {                // async-stage split: issue next tile
            k0 = *(const short8_*)(kp);
            k1 = *(const short8_*)(kp + 8);
            v0 = *(const short8_*)(vp);
            v1 = *(const short8_*)(vp + 8);
            kp += (size_t)64 * D_;
            vp += 64;
        }

        short8_ kf[4][2];
#pragma unroll
        for (int nt = 0; nt < 4; nt++) {
            kf[nt][0] = *(const short8_*)(&Ks[(nt * 16 + ln) * 64 + ((g * 8) ^ px)]);
            kf[nt][1] = *(const short8_*)(&Ks[(nt * 16 + ln) * 64 + ((32 + g * 8) ^ px)]);
        }
        float4_ mk4[4];                        // scaled mask, keys nt*16+g*4..+3
#pragma unroll
        for (int nt = 0; nt < 4; nt++)
            mk4[nt] = *(const float4_*)(&Ms[kt * 64 + nt * 16 + g * 4]);

#pragma unroll
        for (int qg = 0; qg < 2; qg++) {
            float4_ Sf[4];
            __builtin_amdgcn_s_setprio(1);
#pragma unroll
            for (int nt = 0; nt < 4; nt++) {
                float4_ s = (float4_)(0.f);
                s = mfma16(kf[nt][0], aq[qg][0], s);   // swapped: A=K, B=Q
                s = mfma16(kf[nt][1], aq[qg][1], s);
                Sf[nt] = s;
            }
            __builtin_amdgcn_s_setprio(0);
            int prow = wv * 2048 + (qg * 16 + ln) * 64;
#pragma unroll
            for (int nt = 0; nt < 4; nt++) {
                float p0 = __builtin_amdgcn_exp2f(fmaf(Sf[nt][0], C1, mk4[nt][0]));
                float p1 = __builtin_amdgcn_exp2f(fmaf(Sf[nt][1], C1, mk4[nt][1]));
                float p2 = __builtin_amdgcn_exp2f(fmaf(Sf[nt][2], C1, mk4[nt][2]));
                float p3 = __builtin_amdgcn_exp2f(fmaf(Sf[nt][3], C1, mk4[nt][3]));
                // pack 4 f32 -> 4 bf16 (trunc) with two v_perm_b32
                int2v w;
                w[0] = (int)__builtin_amdgcn_perm(__float_as_uint(p1),
                                                  __float_as_uint(p0), 0x07060302u);
                w[1] = (int)__builtin_amdgcn_perm(__float_as_uint(p3),
                                                  __float_as_uint(p2), 0x07060302u);
                *(int2v*)(&PT[prow + ((nt * 16 + g * 4) ^ px)]) = w;
            }
        }

#pragma unroll
        for (int ks = 0; ks < 2; ks++) {
            short8_ vf[4];
#pragma unroll
            for (int dt = 0; dt < 4; dt++)
                vf[dt] = *(const short8_*)(&Vs[(dt * 16 + ln) * 64 + ((ks * 32 + g * 8) ^ px)]);
#pragma unroll
            for (int qg = 0; qg < 2; qg++) {
                short8_ pa = *(const short8_*)(
                    &PT[wv * 2048 + (qg * 16 + ln) * 64 + ((ks * 32 + g * 8) ^ px)]);
                __builtin_amdgcn_s_setprio(1);
#pragma unroll
                for (int dt = 0; dt < 4; dt++)
                    O[qg][dt] = mfma16(pa, vf[dt], O[qg][dt]);
                lsacc[qg] = mfma16(pa, vones, lsacc[qg]);   // row-sum column
                __builtin_amdgcn_s_setprio(0);
            }
        }
    }

    // lsacc[qg][r] = full softmax denominator for q = qg*16 + g*4 + r
    // (identical across ln cols) — exactly the rows this thread stores.
#pragma unroll
    for (int qg = 0; qg < 2; qg++) {
        float inv[4];
#pragma unroll
        for (int r = 0; r < 4; r++) inv[r] = 1.f / lsacc[qg][r];
#pragma unroll
        for (int dt = 0; dt < 4; dt++)
#pragma unroll
            for (int r = 0; r < 4; r++) {
                int q = qt * 128 + wv * 32 + qg * 16 + g * 4 + r;
                float v = O[qg][dt][r] * inv[r];
                ctx[base + (size_t)q * D_ + dt * 16 + ln] = f2b(v);
            }
    }
}

// ---------------- residual + LayerNorm (h in bf16) -------------------------
__global__ __launch_bounds__(256) void ln_kernel(
    const short* __restrict__ hb, const float* __restrict__ x,
    const float* __restrict__ gamma, const float* __restrict__ beta,
    float* __restrict__ out)
{
    int row = blockIdx.x, tid = threadIdx.x;
    const short* hr = hb + (size_t)row * D_;
    const float* xr = x + (size_t)row * D_;
    short4_ h4 = ((const short4_*)hr)[tid];
    float4_ x4 = ((const float4_*)xr)[tid];
    float y[4], s1 = 0.f, s2 = 0.f;
#pragma unroll
    for (int i = 0; i < 4; i++) {
        float hv = __uint_as_float(((unsigned)(unsigned short)h4[i]) << 16);
        float v = hv + x4[i];
        y[i] = v;
        s1 += v;
        s2 += v * v;
    }
#pragma unroll
    for (int sh = 1; sh < 64; sh <<= 1) {
        s1 += __shfl_xor(s1, sh);
        s2 += __shfl_xor(s2, sh);
    }
    __shared__ float ws1[4], ws2[4];
    if ((tid & 63) == 0) { ws1[tid >> 6] = s1; ws2[tid >> 6] = s2; }
    __syncthreads();
    s1 = ws1[0] + ws1[1] + ws1[2] + ws1[3];
    s2 = ws2[0] + ws2[1] + ws2[2] + ws2[3];
    float mu = s1 * (1.f / D_);
    float var = s2 * (1.f / D_) - mu * mu;
    float rs = rsqrtf(var + LN_EPS);
    float4_ g4 = ((const float4_*)gamma)[tid];
    float4_ b4 = ((const float4_*)beta)[tid];
    float4_ o4;
#pragma unroll
    for (int i = 0; i < 4; i++) o4[i] = (y[i] - mu) * rs * g4[i] + b4[i];
    ((float4_*)(out + (size_t)row * D_))[tid] = o4;
}

extern "C" void kernel_launch(void* const* d_in, const int* in_sizes, int n_in,
                              void* d_out, int out_size, void* d_ws, size_t ws_size,
                              hipStream_t stream)
{
    const float* x     = (const float*)d_in[0];
    const float* mask  = (const float*)d_in[1];
    const float* Wq    = (const float*)d_in[2];
    const float* bq    = (const float*)d_in[3];
    const float* Wk    = (const float*)d_in[4];
    const float* bk    = (const float*)d_in[5];
    const float* Wv    = (const float*)d_in[6];
    const float* bv    = (const float*)d_in[7];
    const float* Wo    = (const float*)d_in[8];
    const float* bo    = (const float*)d_in[9];
    const float* gamma = (const float*)d_in[10];
    const float* beta  = (const float*)d_in[11];
    float* out = (float*)d_out;

    char* ws = (char*)d_ws;
    const size_t MB = 1024 * 1024;
    short* Wt  = (short*)(ws);              // 8 MB (Wq,Wk,Wv,Wo transposed)
    short* Xb  = (short*)(ws + 8 * MB);     // 16 MB (reused for Ctx)
    short* Qb  = (short*)(ws + 24 * MB);    // 16 MB (reused for Hh)
    short* Kb  = (short*)(ws + 40 * MB);    // 16 MB
    short* Vtg = (short*)(ws + 56 * MB);    // 16 MB, [bh][dh][s]
    short* Ctx = Xb;
    short* Hh  = Qb;                        // Qb dead after attn

    prep_weights<<<dim3(16, 16, 4), 256, 0, stream>>>(Wq, Wk, Wv, Wo, Wt);
    cast_x<<<(B_ * S_ * D_) / (256 * 4), 256, 0, stream>>>(x, Xb);

    gemm_qkv<<<dim3(64, 8, 3), 256, 0, stream>>>(Xb, Wt, bq, bk, bv, Qb, Kb, Vtg);

    attn<<<dim3(S_ / 128, B_ * H_), 256, 0, stream>>>(Qb, Kb, Vtg, mask, Ctx);

    gemm_out<<<dim3(128, 8), 256, 0, stream>>>(Ctx, Wt + 3 * 1048576, bo, Hh);

    ln_kernel<<<B_ * S_, 256, 0, stream>>>(Hh, x, gamma, beta, out);
}

// Round 9
// 315.826 us; speedup vs baseline: 1.0444x; 1.0078x over previous
//
#include <hip/hip_runtime.h>
#include <hip/hip_bf16.h>
#include <math.h>

// TFAlbertAttention  B=4,S=2048,D=1024,H=16,DH=64, fp32 in/out.
// cast->bf16; QKV projections in ONE grid.z=3 launch of the 128-tile MFMA
//   GEMM; flash attention (R6 structure FROZEN + XCD-decode swizzle: all 16
//   qt-blocks of one bh on one XCD -> per-XCD K/V footprint = 4MB = L2);
//   out GEMM 64x128 tiles; fused residual+LayerNorm (bf16 residual read
//   when workspace permits keeping Xb alive).
// NOTE: kernels use __launch_bounds__(256) with NO min-waves clause —
// (256,4) caps VGPR at 128 -> ~1.5GB scratch spill (round 1: 118->365us).
// NOTE: attn structure is FROZEN at the R6 variant. Measured across 7
// restructurings (118.7/365/137.6/121.3/136.7/138.2/119.4/129.9):
//   - ds_write staging + 2 barriers/tile BEATS global_load_lds dbuf +
//     1 barrier (R4/R7: LDS 49KB -> 3 blocks/CU vs 4 needed -> tail pass).
//   - interleaved PV (vf shared across qg) beats qg-sequential (R4).
//   - QBLK=128/4-wave beats QBLK=64 (R5: 2x waves re-stage all K/V).
//   - row-sums via MFMA-ones beats shuffle tree (R3, also absmax 2x better).
// NOTE: attn run-to-run noise is ~±4us (R6 vs R8, identical binary).
// NOTE: no XCD swizzle in GEMMs — problem is L3-resident (round 5 negative);
// the attn swizzle is different: it groups K/V SHARERS onto one L2.

#define B_ 4
#define S_ 2048
#define D_ 1024
#define H_ 16
#define DH_ 64
#define LN_EPS 1e-12f

typedef __attribute__((ext_vector_type(8))) short short8_;
typedef __attribute__((ext_vector_type(4))) short short4_;
typedef __attribute__((ext_vector_type(4))) float float4_;
typedef __attribute__((ext_vector_type(2))) int int2v;

__device__ inline short f2b(float x) {          // RNE
    unsigned u = __float_as_uint(x);
    unsigned r = (u + 0x7fffu + ((u >> 16) & 1u)) >> 16;
    return (short)r;
}

__device__ inline float4_ mfma16(short8_ a, short8_ b, float4_ c) {
    return __builtin_amdgcn_mfma_f32_16x16x32_bf16(a, b, c, 0, 0, 0);
}

#define GLOAD16(g, l)                                                      \
    __builtin_amdgcn_global_load_lds(                                      \
        (const __attribute__((address_space(1))) void*)(g),                \
        (__attribute__((address_space(3))) void*)(l), 16, 0, 0)

// ---------------- weight transpose + cast: W[k][n] fp32 -> Wt[n][k] bf16 ----
__global__ __launch_bounds__(256) void prep_weights(
    const float* __restrict__ W0, const float* __restrict__ W1,
    const float* __restrict__ W2, const float* __restrict__ W3,
    short* __restrict__ Wt)
{
    const float* W = (blockIdx.z == 0) ? W0 : (blockIdx.z == 1) ? W1
                   : (blockIdx.z == 2) ? W2 : W3;
    short* out = Wt + (size_t)blockIdx.z * (1024 * 1024);
    __shared__ float T[64][65];
    int tx = threadIdx.x & 63, ty = threadIdx.x >> 6;
    int k0 = blockIdx.x * 64, n0 = blockIdx.y * 64;
#pragma unroll
    for (int i = 0; i < 16; i++) {
        int kk = ty + i * 4;
        T[kk][tx] = W[(size_t)(k0 + kk) * 1024 + n0 + tx];
    }
    __syncthreads();
#pragma unroll
    for (int i = 0; i < 16; i++) {
        int nn = ty + i * 4;
        out[(size_t)(n0 + nn) * 1024 + k0 + tx] = f2b(T[tx][nn]);
    }
}

// ---------------- x fp32 -> bf16 ----------------
__global__ __launch_bounds__(256) void cast_x(const float* __restrict__ x,
                                              short* __restrict__ xb)
{
    int i = blockIdx.x * 256 + threadIdx.x;
    float4_ v = ((const float4_*)x)[i];
    short4_ o;
#pragma unroll
    for (int j = 0; j < 4; j++) o[j] = f2b(v[j]);
    ((short4_*)xb)[i] = o;
}

// ---------------- fused QKV GEMM, grid (64, 8, 3) --------------------------
// z selects weight slice + destination: 0->Qb(+bq), 1->Kb(+bk), 2->Vtg(+bv,
// transposed per-head via T[64][132] aliased onto As/Bs LDS, dead after
// the K-loop). 128x128 tiles, BK=64 as two 32-sub-buffers, global_load_lds.
__global__ __launch_bounds__(256) void gemm_qkv(
    const short* __restrict__ A, const short* __restrict__ Wt,
    const float* __restrict__ bq, const float* __restrict__ bk,
    const float* __restrict__ bv,
    short* __restrict__ Qb, short* __restrict__ Kb, short* __restrict__ Vtg)
{
    __shared__ __align__(16) short SH[4 * 128 * 32];   // 32 KB
    short* As = SH;                                    // [2][128*32]
    short* Bs = SH + 2 * 128 * 32;                     // [2][128*32]
    const int K = D_;
    int tid = threadIdx.x;
    int wv = tid >> 6, lane = tid & 63;
    int g = lane >> 4, ln = lane & 15;
    int wm = wv & 1, wn = wv >> 1;
    int z = blockIdx.z;
    int mtile = blockIdx.x * 128, ntile = blockIdx.y * 128;
    const short* Bt = Wt + (size_t)z * (1024 * 1024);

    int srow = wv * 32 + (lane >> 2);
    int scol = (lane & 3) * 8;
    const short* agp = A + (size_t)(mtile + srow) * K + scol;
    const short* bgp = Bt + (size_t)(ntile + srow) * K + scol;

    float4_ acc[4][4];
#pragma unroll
    for (int i = 0; i < 4; i++)
#pragma unroll
        for (int j = 0; j < 4; j++) acc[i][j] = (float4_)(0.f);

    for (int k0 = 0; k0 < K; k0 += 64) {
        if (k0) __syncthreads();
#pragma unroll
        for (int hf = 0; hf < 2; hf++) {
            GLOAD16(agp + k0 + hf * 32, &As[hf * 4096 + (wv * 32) * 32]);
            GLOAD16(agp + k0 + hf * 32 + (size_t)16 * K, &As[hf * 4096 + (wv * 32 + 16) * 32]);
            GLOAD16(bgp + k0 + hf * 32, &Bs[hf * 4096 + (wv * 32) * 32]);
            GLOAD16(bgp + k0 + hf * 32 + (size_t)16 * K, &Bs[hf * 4096 + (wv * 32 + 16) * 32]);
        }
        __syncthreads();
#pragma unroll
        for (int hf = 0; hf < 2; hf++) {
            short8_ am[4], bn[4];
#pragma unroll
            for (int mt = 0; mt < 4; mt++)
                am[mt] = *(const short8_*)(&As[hf * 4096 + (wm * 64 + mt * 16 + ln) * 32 + g * 8]);
#pragma unroll
            for (int nt = 0; nt < 4; nt++)
                bn[nt] = *(const short8_*)(&Bs[hf * 4096 + (wn * 64 + nt * 16 + ln) * 32 + g * 8]);
#pragma unroll
            for (int mt = 0; mt < 4; mt++)
#pragma unroll
                for (int nt = 0; nt < 4; nt++)
                    acc[mt][nt] = mfma16(am[mt], bn[nt], acc[mt][nt]);
        }
    }

    if (z == 2) {
        // V: transpose per-head -> Vtg[bh][dh][s]. T[64][132] aliased on SH.
        short* T = SH;
        int b = mtile >> 11, s0 = mtile & 2047;
#pragma unroll
        for (int p = 0; p < 2; p++) {
            __syncthreads();
            if (wn == p) {
#pragma unroll
                for (int nt = 0; nt < 4; nt++) {
                    float bsv = bv[ntile + p * 64 + nt * 16 + ln];
#pragma unroll
                    for (int mt = 0; mt < 4; mt++) {
                        short4_ o;
#pragma unroll
                        for (int r = 0; r < 4; r++) o[r] = f2b(acc[mt][nt][r] + bsv);
                        *(short4_*)(&T[(nt * 16 + ln) * 132 + wm * 64 + mt * 16 + g * 4]) = o;
                    }
                }
            }
            __syncthreads();
            int h = (ntile >> 6) + p;
            int row = tid >> 2, colb = (tid & 3) * 32;
            size_t obase = ((size_t)(b * H_ + h)) * (DH_ * S_) + (size_t)row * S_ + s0 + colb;
#pragma unroll
            for (int c = 0; c < 4; c++)
                *(short8_*)(Vtg + obase + c * 8) = *(const short8_*)(&T[row * 132 + colb + c * 8]);
        }
    } else {
        short* Cout = z ? Kb : Qb;
        const float* bias = z ? bk : bq;
#pragma unroll
        for (int nt = 0; nt < 4; nt++) {
            int n = ntile + wn * 64 + nt * 16 + ln;
            float bsv = bias[n];
#pragma unroll
            for (int mt = 0; mt < 4; mt++) {
#pragma unroll
                for (int r = 0; r < 4; r++) {
                    int m = mtile + wm * 64 + mt * 16 + g * 4 + r;
                    Cout[(size_t)m * D_ + n] = f2b(acc[mt][nt][r] + bsv);
                }
            }
        }
    }
}

// ---------------- out GEMM: Ctx[8192,1024] x Wo^T + bo -> bf16 -------------
// 64x128 tiles, grid (128, 8) = 1024 blocks -> 4 blocks/CU demand.
__global__ __launch_bounds__(256) void gemm_out(
    const short* __restrict__ A, const short* __restrict__ Bt,
    const float* __restrict__ bias, short* __restrict__ Cout)
{
    __shared__ __align__(16) short As[2][64 * 32];    // 8 KB
    __shared__ __align__(16) short Bs[2][128 * 32];   // 16 KB
    const int K = D_;
    int tid = threadIdx.x;
    int wv = tid >> 6, lane = tid & 63;
    int g = lane >> 4, ln = lane & 15;
    int wm = wv & 1, wn = wv >> 1;
    int mtile = blockIdx.x * 64, ntile = blockIdx.y * 128;

    int arow = wv * 16 + (lane >> 2);    // wave stages 16 A-rows
    int brow = wv * 32 + (lane >> 2);    // wave stages 32 B-rows (2 gloads)
    int scol = (lane & 3) * 8;
    const short* agp = A + (size_t)(mtile + arow) * K + scol;
    const short* bgp = Bt + (size_t)(ntile + brow) * K + scol;

    float4_ acc[2][4];
#pragma unroll
    for (int i = 0; i < 2; i++)
#pragma unroll
        for (int j = 0; j < 4; j++) acc[i][j] = (float4_)(0.f);

    for (int k0 = 0; k0 < K; k0 += 64) {
        if (k0) __syncthreads();
#pragma unroll
        for (int hf = 0; hf < 2; hf++) {
            GLOAD16(agp + k0 + hf * 32, &As[hf][(wv * 16) * 32]);
            GLOAD16(bgp + k0 + hf * 32, &Bs[hf][(wv * 32) * 32]);
            GLOAD16(bgp + k0 + hf * 32 + (size_t)16 * K, &Bs[hf][(wv * 32 + 16) * 32]);
        }
        __syncthreads();
#pragma unroll
        for (int hf = 0; hf < 2; hf++) {
            short8_ am[2], bn[4];
#pragma unroll
            for (int mt = 0; mt < 2; mt++)
                am[mt] = *(const short8_*)(&As[hf][(wm * 32 + mt * 16 + ln) * 32 + g * 8]);
#pragma unroll
            for (int nt = 0; nt < 4; nt++)
                bn[nt] = *(const short8_*)(&Bs[hf][(wn * 64 + nt * 16 + ln) * 32 + g * 8]);
#pragma unroll
            for (int mt = 0; mt < 2; mt++)
#pragma unroll
                for (int nt = 0; nt < 4; nt++)
                    acc[mt][nt] = mfma16(am[mt], bn[nt], acc[mt][nt]);
        }
    }

#pragma unroll
    for (int nt = 0; nt < 4; nt++) {
        int n = ntile + wn * 64 + nt * 16 + ln;
        float bsv = bias[n];
#pragma unroll
        for (int mt = 0; mt < 2; mt++) {
#pragma unroll
            for (int r = 0; r < 4; r++) {
                int m = mtile + wm * 32 + mt * 16 + g * 4 + r;
                Cout[(size_t)m * D_ + n] = f2b(acc[mt][nt][r] + bsv);
            }
        }
    }
}

// ---------------- flash attention (R6 structure — FROZEN) ------------------
// grid (16, 64) = 1024 blocks. XCD-DECODE SWIZZLE: hardware round-robins
// flat block id across 8 XCDs (flat%8 = xcd); decode so all 16 qt-blocks of
// one bh land on ONE XCD: xcd = flat&7, j = flat>>3, bh = xcd*8 + (j>>4),
// qt = j&15 (bijective; 8 bh per XCD -> K/V footprint 8*512KB = 4MB = L2).
// block 256 = 4 waves; wave owns 32 q rows (2 groups of 16).
// SWAPPED QK^T: S^T = mfma(Kfrag, Qfrag) -> lane holds P[q=ln][4 consecutive
// keys per nt] -> v_perm bf16 pack + b64 P^T stores, b128 A-frag reads for PV.
// Row-sums via an extra MFMA against ones. Mask pre-scaled in LDS.
// All LDS tiles XOR-swizzled. K/V reg-prefetch one tile ahead.
__global__ __launch_bounds__(256) void attn(
    const short* __restrict__ Qb, const short* __restrict__ Kb,
    const short* __restrict__ Vtg, const float* __restrict__ mask,
    short* __restrict__ ctx)
{
    __shared__ __align__(16) short Ks[64 * 64];       // [key][d], swizzled
    __shared__ __align__(16) short Vs[64 * 64];       // [d][key], swizzled
    __shared__ __align__(16) short PT[4 * 32 * 64];   // per-wave [q][key], swizzled
    __shared__ __align__(16) float Ms[S_];            // mask[b] * log2(e)
    int tid = threadIdx.x, wv = tid >> 6, lane = tid & 63;
    int g = lane >> 4, ln = lane & 15;

    int flat = blockIdx.y * 16 + blockIdx.x;          // 0..1023
    int xcd = flat & 7, j = flat >> 3;
    int bh = (xcd << 3) + (j >> 4);                   // 8 bh per XCD
    int qt = j & 15;
    int b = bh >> 4, h = bh & 15;
    const size_t base = (size_t)b * S_ * D_ + h * DH_;
    const size_t vbase = (size_t)bh * (DH_ * S_);
    const float C1 = 0.18033688f;       // 0.125 * log2(e)
    const float LOG2E = 1.44269504f;
    const int px = (ln & 7) << 3;       // read-side XOR (row&7 == ln&7)

    // stage pre-scaled mask row into LDS (once per block)
#pragma unroll
    for (int i = 0; i < 2; i++) {
        float4_ mv = *(const float4_*)(mask + (size_t)b * S_ + i * 1024 + tid * 4);
        *(float4_*)(&Ms[i * 1024 + tid * 4]) = mv * LOG2E;
    }

    short8_ aq[2][2];
#pragma unroll
    for (int qg = 0; qg < 2; qg++) {
        int qrow = qt * 128 + wv * 32 + qg * 16 + ln;
        aq[qg][0] = *(const short8_*)(Qb + base + (size_t)qrow * D_ + g * 8);
        aq[qg][1] = *(const short8_*)(Qb + base + (size_t)qrow * D_ + 32 + g * 8);
    }

    short8_ vones;                      // bf16 1.0 x8 (B-operand for row-sums)
#pragma unroll
    for (int j2 = 0; j2 < 8; j2++) vones[j2] = (short)0x3F80;

    float4_ O[2][4];
    float4_ lsacc[2];
#pragma unroll
    for (int qg = 0; qg < 2; qg++) {
        lsacc[qg] = (float4_)(0.f);
#pragma unroll
        for (int i = 0; i < 4; i++) O[qg][i] = (float4_)(0.f);
    }

    // staging addresses (loop-invariant)
    int srow = tid >> 2, scol = (tid & 3) * 16;
    int sw0 = srow * 64 + (scol ^ ((srow & 7) << 3));
    int sw1 = srow * 64 + ((scol + 8) ^ ((srow & 7) << 3));

    const short* kp = Kb + base + (size_t)srow * D_ + scol;
    const short* vp = Vtg + vbase + (size_t)srow * S_ + scol;

    // prologue: load tile 0 into regs
    short8_ k0 = *(const short8_*)(kp);
    short8_ k1 = *(const short8_*)(kp + 8);
    short8_ v0 = *(const short8_*)(vp);
    short8_ v1 = *(const short8_*)(vp + 8);
    kp += (size_t)64 * D_;
    vp += 64;

    for (int kt = 0; kt < S_ / 64; kt++) {
        __syncthreads();                       // all waves done reading prev tile
        *(short8_*)(&Ks[sw0]) = k0;
        *(short8_*)(&Ks[sw1]) = k1;
        *(short8_*)(&Vs[sw0]) = v0;
        *(short8_*)(&Vs[sw1]) = v1;
        __syncthreads();
        if (kt < S_ / 64 - 1) {                // async-stage split: issue next tile
            k0 = *(const short8_*)(kp);
            k1 = *(const short8_*)(kp + 8);
            v0 = *(const short8_*)(vp);
            v1 = *(const short8_*)(vp + 8);
            kp += (size_t)64 * D_;
            vp += 64;
        }

        short8_ kf[4][2];
#pragma unroll
        for (int nt = 0; nt < 4; nt++) {
            kf[nt][0] = *(const short8_*)(&Ks[(nt * 16 + ln) * 64 + ((g * 8) ^ px)]);
            kf[nt][1] = *(const short8_*)(&Ks[(nt * 16 + ln) * 64 + ((32 + g * 8) ^ px)]);
        }
        float4_ mk4[4];                        // scaled mask, keys nt*16+g*4..+3
#pragma unroll
        for (int nt = 0; nt < 4; nt++)
            mk4[nt] = *(const float4_*)(&Ms[kt * 64 + nt * 16 + g * 4]);

#pragma unroll
        for (int qg = 0; qg < 2; qg++) {
            float4_ Sf[4];
            __builtin_amdgcn_s_setprio(1);
#pragma unroll
            for (int nt = 0; nt < 4; nt++) {
                float4_ s = (float4_)(0.f);
                s = mfma16(kf[nt][0], aq[qg][0], s);   // swapped: A=K, B=Q
                s = mfma16(kf[nt][1], aq[qg][1], s);
                Sf[nt] = s;
            }
            __builtin_amdgcn_s_setprio(0);
            int prow = wv * 2048 + (qg * 16 + ln) * 64;
#pragma unroll
            for (int nt = 0; nt < 4; nt++) {
                float p0 = __builtin_amdgcn_exp2f(fmaf(Sf[nt][0], C1, mk4[nt][0]));
                float p1 = __builtin_amdgcn_exp2f(fmaf(Sf[nt][1], C1, mk4[nt][1]));
                float p2 = __builtin_amdgcn_exp2f(fmaf(Sf[nt][2], C1, mk4[nt][2]));
                float p3 = __builtin_amdgcn_exp2f(fmaf(Sf[nt][3], C1, mk4[nt][3]));
                // pack 4 f32 -> 4 bf16 (trunc) with two v_perm_b32
                int2v w;
                w[0] = (int)__builtin_amdgcn_perm(__float_as_uint(p1),
                                                  __float_as_uint(p0), 0x07060302u);
                w[1] = (int)__builtin_amdgcn_perm(__float_as_uint(p3),
                                                  __float_as_uint(p2), 0x07060302u);
                *(int2v*)(&PT[prow + ((nt * 16 + g * 4) ^ px)]) = w;
            }
        }

#pragma unroll
        for (int ks = 0; ks < 2; ks++) {
            short8_ vf[4];
#pragma unroll
            for (int dt = 0; dt < 4; dt++)
                vf[dt] = *(const short8_*)(&Vs[(dt * 16 + ln) * 64 + ((ks * 32 + g * 8) ^ px)]);
#pragma unroll
            for (int qg = 0; qg < 2; qg++) {
                short8_ pa = *(const short8_*)(
                    &PT[wv * 2048 + (qg * 16 + ln) * 64 + ((ks * 32 + g * 8) ^ px)]);
                __builtin_amdgcn_s_setprio(1);
#pragma unroll
                for (int dt = 0; dt < 4; dt++)
                    O[qg][dt] = mfma16(pa, vf[dt], O[qg][dt]);
                lsacc[qg] = mfma16(pa, vones, lsacc[qg]);   // row-sum column
                __builtin_amdgcn_s_setprio(0);
            }
        }
    }

    // lsacc[qg][r] = full softmax denominator for q = qg*16 + g*4 + r
    // (identical across ln cols) — exactly the rows this thread stores.
#pragma unroll
    for (int qg = 0; qg < 2; qg++) {
        float inv[4];
#pragma unroll
        for (int r = 0; r < 4; r++) inv[r] = 1.f / lsacc[qg][r];
#pragma unroll
        for (int dt = 0; dt < 4; dt++)
#pragma unroll
            for (int r = 0; r < 4; r++) {
                int q = qt * 128 + wv * 32 + qg * 16 + g * 4 + r;
                float v = O[qg][dt][r] * inv[r];
                ctx[base + (size_t)q * D_ + dt * 16 + ln] = f2b(v);
            }
    }
}

// ---------------- residual + LayerNorm (h in bf16) -------------------------
// XB=1: residual read from bf16 Xb (16MB instead of 32MB fp32) — used when
// the workspace is big enough to keep Xb alive alongside Ctx.
template <int XB>
__global__ __launch_bounds__(256) void ln_kernel(
    const short* __restrict__ hb, const float* __restrict__ x,
    const short* __restrict__ xb,
    const float* __restrict__ gamma, const float* __restrict__ beta,
    float* __restrict__ out)
{
    int row = blockIdx.x, tid = threadIdx.x;
    const short* hr = hb + (size_t)row * D_;
    short4_ h4 = ((const short4_*)hr)[tid];
    float y[4], s1 = 0.f, s2 = 0.f;
    if constexpr (XB) {
        short4_ x4 = ((const short4_*)(xb + (size_t)row * D_))[tid];
#pragma unroll
        for (int i = 0; i < 4; i++) {
            float hv = __uint_as_float(((unsigned)(unsigned short)h4[i]) << 16);
            float xv = __uint_as_float(((unsigned)(unsigned short)x4[i]) << 16);
            float v = hv + xv;
            y[i] = v; s1 += v; s2 += v * v;
        }
    } else {
        float4_ x4 = ((const float4_*)(x + (size_t)row * D_))[tid];
#pragma unroll
        for (int i = 0; i < 4; i++) {
            float hv = __uint_as_float(((unsigned)(unsigned short)h4[i]) << 16);
            float v = hv + x4[i];
            y[i] = v; s1 += v; s2 += v * v;
        }
    }
#pragma unroll
    for (int sh = 1; sh < 64; sh <<= 1) {
        s1 += __shfl_xor(s1, sh);
        s2 += __shfl_xor(s2, sh);
    }
    __shared__ float ws1[4], ws2[4];
    if ((tid & 63) == 0) { ws1[tid >> 6] = s1; ws2[tid >> 6] = s2; }
    __syncthreads();
    s1 = ws1[0] + ws1[1] + ws1[2] + ws1[3];
    s2 = ws2[0] + ws2[1] + ws2[2] + ws2[3];
    float mu = s1 * (1.f / D_);
    float var = s2 * (1.f / D_) - mu * mu;
    float rs = rsqrtf(var + LN_EPS);
    float4_ g4 = ((const float4_*)gamma)[tid];
    float4_ b4 = ((const float4_*)beta)[tid];
    float4_ o4;
#pragma unroll
    for (int i = 0; i < 4; i++) o4[i] = (y[i] - mu) * rs * g4[i] + b4[i];
    ((float4_*)(out + (size_t)row * D_))[tid] = o4;
}

extern "C" void kernel_launch(void* const* d_in, const int* in_sizes, int n_in,
                              void* d_out, int out_size, void* d_ws, size_t ws_size,
                              hipStream_t stream)
{
    const float* x     = (const float*)d_in[0];
    const float* mask  = (const float*)d_in[1];
    const float* Wq    = (const float*)d_in[2];
    const float* bq    = (const float*)d_in[3];
    const float* Wk    = (const float*)d_in[4];
    const float* bk    = (const float*)d_in[5];
    const float* Wv    = (const float*)d_in[6];
    const float* bv    = (const float*)d_in[7];
    const float* Wo    = (const float*)d_in[8];
    const float* bo    = (const float*)d_in[9];
    const float* gamma = (const float*)d_in[10];
    const float* beta  = (const float*)d_in[11];
    float* out = (float*)d_out;

    char* ws = (char*)d_ws;
    const size_t MB = 1024 * 1024;
    short* Wt  = (short*)(ws);              // 8 MB (Wq,Wk,Wv,Wo transposed)
    short* Xb  = (short*)(ws + 8 * MB);     // 16 MB
    short* Qb  = (short*)(ws + 24 * MB);    // 16 MB (reused for Hh)
    short* Kb  = (short*)(ws + 40 * MB);    // 16 MB
    short* Vtg = (short*)(ws + 56 * MB);    // 16 MB, [bh][dh][s]
    short* Hh  = Qb;                        // Qb dead after attn

    // If the workspace has a 6th 16MB slot, keep Xb alive (ln reads bf16
    // residual = half the traffic); else reuse Xb for Ctx as before.
    int big = ws_size >= 88 * MB;
    short* Ctx = big ? (short*)(ws + 72 * MB) : Xb;

    prep_weights<<<dim3(16, 16, 4), 256, 0, stream>>>(Wq, Wk, Wv, Wo, Wt);
    cast_x<<<(B_ * S_ * D_) / (256 * 4), 256, 0, stream>>>(x, Xb);

    gemm_qkv<<<dim3(64, 8, 3), 256, 0, stream>>>(Xb, Wt, bq, bk, bv, Qb, Kb, Vtg);

    attn<<<dim3(S_ / 128, B_ * H_), 256, 0, stream>>>(Qb, Kb, Vtg, mask, Ctx);

    gemm_out<<<dim3(128, 8), 256, 0, stream>>>(Ctx, Wt + 3 * 1048576, bo, Hh);

    if (big)
        ln_kernel<1><<<B_ * S_, 256, 0, stream>>>(Hh, x, Xb, gamma, beta, out);
    else
        ln_kernel<0><<<B_ * S_, 256, 0, stream>>>(Hh, x, Xb, gamma, beta, out);
}